// Round 3
// baseline (210.725 us; speedup 1.0000x reference)
//
#include <hip/hip_runtime.h>
#include <hip/hip_bf16.h>

#define NGRAPH 32
#define NHEAD 8
#define EMB 512
#define NNODES 16384
#define NPG 512
#define LQ 1024
#define PST 520   // padded LDS row stride (ushorts): 520*2B = 260 words ≡ 4 mod 32 -> 2-way (free)

typedef __attribute__((ext_vector_type(8))) short short8;
typedef __attribute__((ext_vector_type(4))) float f32x4;

static __device__ __forceinline__ unsigned short f2bf(float f) {
  union { float f; unsigned u; } v; v.f = f;
  unsigned r = (v.u + 0x7fffu + ((v.u >> 16) & 1u)) >> 16;
  return (unsigned short)r;
}

// async global->LDS, 16B per lane; LDS dest = wave-uniform base + lane*16
static __device__ __forceinline__ void gload_lds16(const ushort* g, ushort* l) {
  __builtin_amdgcn_global_load_lds(
      (const __attribute__((address_space(1))) unsigned*)g,
      (__attribute__((address_space(3))) unsigned*)l, 16, 0, 0);
}

// ---- x [N,E] f32 -> xb [N,E] bf16 AND xbT [E,N] bf16 (one read of x) ----
__global__ void prep_x(const float* __restrict__ x, ushort* __restrict__ xb,
                       ushort* __restrict__ xbT) {
  __shared__ ushort tile[32][33];
  int bc = blockIdx.x;   // E/32
  int br = blockIdx.y;   // N/32
  int t = threadIdx.x, lr = t >> 5, lc = t & 31;
#pragma unroll
  for (int p = 0; p < 4; ++p) {
    int r = lr + p * 8;
    long gi = (long)(br * 32 + r) * EMB + bc * 32 + lc;
    ushort b = f2bf(x[gi]);
    xb[gi] = b;
    tile[r][lc] = b;
  }
  __syncthreads();
#pragma unroll
  for (int p = 0; p < 4; ++p) {
    int r = lr + p * 8;
    xbT[(long)(bc * 32 + r) * NNODES + br * 32 + lc] = tile[lc][r];
  }
}

// ---- wv, wo f32 -> bf16; block 512 writes batchcent ----
__global__ void prep_w(const float* __restrict__ wv, const float* __restrict__ wo,
                       ushort* __restrict__ wvb, ushort* __restrict__ wob,
                       float* __restrict__ bc) {
  int b = blockIdx.x;
  if (b == 512) {
    int i = threadIdx.x;
#pragma unroll
    for (int p = 0; p < 4; ++p) bc[i + p * 256] = (float)((i + p * 256) >> 5);
    return;
  }
  const float* src = (b < 256) ? wv : wo;
  ushort* dst = (b < 256) ? wvb : wob;
  int i = ((b & 255) * 256 + threadIdx.x) * 4;
  float4 v = *reinterpret_cast<const float4*>(src + i);
  ushort4 o;
  o.x = f2bf(v.x); o.y = f2bf(v.y); o.z = f2bf(v.z); o.w = f2bf(v.w);
  *reinterpret_cast<ushort4*>(dst + i) = o;
}

// ---- fused q_proj + pc_proj: PC[h*32+l, k] = scale * (xc[l]·Wq_h^T + bq_h) · Wk_h ----
// grid 64 = (ks<<3) + h ; each block recomputes Q_h [32x64] then its 64-wide k-slice.
__global__ void qpc(const float* __restrict__ xc, const float* __restrict__ wq,
                    const float* __restrict__ bq, const float* __restrict__ wk,
                    ushort* __restrict__ PCb) {
  __shared__ float Qh[32][64];
  int h = blockIdx.x & 7, ks = blockIdx.x >> 3;
  int tidx = threadIdx.x;
#pragma unroll
  for (int p = 0; p < 8; ++p) {
    int o = tidx + p * 256;       // 0..2047
    int l = o >> 6, d = o & 63;
    const float4* xr = reinterpret_cast<const float4*>(xc + l * EMB);
    const float4* wr = reinterpret_cast<const float4*>(wq + (long)(h * 64 + d) * EMB);
    float s = 0.f;
#pragma unroll 4
    for (int j = 0; j < 128; ++j) {
      float4 a = xr[j], b = wr[j];
      s += a.x * b.x + a.y * b.y + a.z * b.z + a.w * b.w;
    }
    Qh[l][d] = s + bq[h * 64 + d];
  }
  __syncthreads();
#pragma unroll
  for (int p = 0; p < 8; ++p) {
    int o = tidx + p * 256;
    int l = o >> 6, kk = ks * 64 + (o & 63);
    float s = 0.f;
#pragma unroll 8
    for (int d = 0; d < 64; ++d)
      s += Qh[l][d] * wk[(long)(h * 64 + d) * EMB + kk];
    PCb[(h * 32 + l) * EMB + kk] = f2bf(s * 0.125f);
  }
}

// ---- fused attention per (graph, head), 8 waves, LDS-staged, double-buffered ----
__global__ __launch_bounds__(512) void fused_attn(
    const ushort* __restrict__ PCb, const ushort* __restrict__ xb,
    const ushort* __restrict__ xbT, const ushort* __restrict__ wvb,
    const float* __restrict__ bvb, ushort* __restrict__ aout) {
  __shared__ ushort PCl[32 * PST];      // PC_h padded
  __shared__ ushort PBuf[32 * PST];     // attn, then R
  __shared__ ushort Bbuf[2][16384];     // double-buffered B chunk [512 rows][32 K]
  __shared__ float rmax[32][8];
  __shared__ float rsum[32][8];

  const int g = blockIdx.x & 31, h = blockIdx.x >> 5;  // g%8 == block%8 -> graph pinned to XCD
  const int t = threadIdx.x, w = t >> 6, lane = t & 63;
  const int lr = lane & 15, grp = lane >> 4;
  const int koU = grp * 8;                  // ushort offset of this lane-group's K-part

  const ushort* xg  = xb  + (long)g * NPG * EMB;
  const ushort* xTg = xbT + g * NPG;

  const int srow  = w * 16 + (lane >> 2);   // staging row within q-block
  const int spart = lane & 3;

  // stage chunk c (K cols c*32..c*32+32) of phase-1 B (xb_g) into Bbuf[db]
  // pre-swizzled source: LDS linear, global part = part ^ ((row>>1)&3)
  auto STAGE1 = [&](int c, int db) {
#pragma unroll
    for (int q = 0; q < 4; ++q) {
      int row = q * 128 + srow;
      int psrc = spart ^ ((row >> 1) & 3);
      gload_lds16(xg + (long)row * EMB + c * 32 + psrc * 8,
                  &Bbuf[db][q * 4096 + w * 512]);
    }
  };
  auto STAGE3 = [&](int c, int db) {
#pragma unroll
    for (int q = 0; q < 4; ++q) {
      int row = q * 128 + srow;            // E index
      int psrc = spart ^ ((row >> 1) & 3);
      gload_lds16(xTg + (long)row * NNODES + c * 32 + psrc * 8,
                  &Bbuf[db][q * 4096 + w * 512]);
    }
  };

  STAGE1(0, 0);
  // stage PC_h into padded LDS (one-time, reg-staged)
  {
    const ushort* pc = PCb + h * 32 * EMB;
#pragma unroll
    for (int p = 0; p < 4; ++p) {
      int u = t + p * 512;                 // 16B units, 2048 total
      int row = u >> 6, col = (u & 63) * 8;
      *reinterpret_cast<short8*>(&PCl[row * PST + col]) =
          *reinterpret_cast<const short8*>(pc + row * EMB + col);
    }
  }
  __syncthreads();

  // ---------- phase 1: S = PC_h · X_g^T  (M=32, N=512 nodes, K=512) ----------
  f32x4 acc[2][4];
#pragma unroll
  for (int i = 0; i < 2; ++i)
#pragma unroll
    for (int j = 0; j < 4; ++j) acc[i][j] = (f32x4)(0.0f);

#pragma unroll
  for (int c = 0; c < 16; ++c) {
    int db = c & 1;
    if (c < 15) STAGE1(c + 1, db ^ 1);
    short8 a0 = *reinterpret_cast<const short8*>(&PCl[lr * PST + c * 32 + koU]);
    short8 a1 = *reinterpret_cast<const short8*>(&PCl[(16 + lr) * PST + c * 32 + koU]);
    short8 bv[4];
#pragma unroll
    for (int j = 0; j < 4; ++j) {
      int n = w * 64 + j * 16 + lr;
      int psrc = grp ^ ((n >> 1) & 3);
      bv[j] = *reinterpret_cast<const short8*>(&Bbuf[db][n * 32 + psrc * 8]);
    }
#pragma unroll
    for (int j = 0; j < 4; ++j) {
      acc[0][j] = __builtin_amdgcn_mfma_f32_16x16x32_bf16(a0, bv[j], acc[0][j], 0, 0, 0);
      acc[1][j] = __builtin_amdgcn_mfma_f32_16x16x32_bf16(a1, bv[j], acc[1][j], 0, 0, 0);
    }
    __syncthreads();
  }

  // ---------- phase 2: softmax (rows shared, cols split 8 ways) ----------
#pragma unroll
  for (int i = 0; i < 2; ++i)
#pragma unroll
    for (int r = 0; r < 4; ++r) {
      float m = fmaxf(fmaxf(acc[i][0][r], acc[i][1][r]), fmaxf(acc[i][2][r], acc[i][3][r]));
      m = fmaxf(m, __shfl_xor(m, 1)); m = fmaxf(m, __shfl_xor(m, 2));
      m = fmaxf(m, __shfl_xor(m, 4)); m = fmaxf(m, __shfl_xor(m, 8));
      if (lr == 0) rmax[i * 16 + grp * 4 + r][w] = m;
    }
  __syncthreads();
#pragma unroll
  for (int i = 0; i < 2; ++i)
#pragma unroll
    for (int r = 0; r < 4; ++r) {
      int row = i * 16 + grp * 4 + r;
      float m = rmax[row][0];
#pragma unroll
      for (int q = 1; q < 8; ++q) m = fmaxf(m, rmax[row][q]);
      float s = 0.f;
#pragma unroll
      for (int j = 0; j < 4; ++j) {
        float e = __expf(acc[i][j][r] - m);
        acc[i][j][r] = e;
        s += e;
      }
      s += __shfl_xor(s, 1); s += __shfl_xor(s, 2);
      s += __shfl_xor(s, 4); s += __shfl_xor(s, 8);
      if (lr == 0) rsum[row][w] = s;
    }
  __syncthreads();
#pragma unroll
  for (int i = 0; i < 2; ++i)
#pragma unroll
    for (int r = 0; r < 4; ++r) {
      int row = i * 16 + grp * 4 + r;
      float tot = rsum[row][0];
#pragma unroll
      for (int q = 1; q < 8; ++q) tot += rsum[row][q];
      float inv = 1.f / tot;
#pragma unroll
      for (int j = 0; j < 4; ++j)
        PBuf[row * PST + w * 64 + j * 16 + lr] = f2bf(acc[i][j][r] * inv);
    }
  STAGE3(0, 0);   // Bbuf[0] reads finished at iter-14 barrier; safe
  __syncthreads();

  // ---------- phase 3: R = attn · X_g  (M=32, N=512 E, K=512 nodes) ----------
  f32x4 acc2[2][4];
#pragma unroll
  for (int i = 0; i < 2; ++i)
#pragma unroll
    for (int j = 0; j < 4; ++j) acc2[i][j] = (f32x4)(0.0f);

#pragma unroll
  for (int c = 0; c < 16; ++c) {
    int db = c & 1;
    if (c < 15) STAGE3(c + 1, db ^ 1);
    short8 a0 = *reinterpret_cast<const short8*>(&PBuf[lr * PST + c * 32 + koU]);
    short8 a1 = *reinterpret_cast<const short8*>(&PBuf[(16 + lr) * PST + c * 32 + koU]);
    short8 bv[4];
#pragma unroll
    for (int j = 0; j < 4; ++j) {
      int e = w * 64 + j * 16 + lr;
      int psrc = grp ^ ((e >> 1) & 3);
      bv[j] = *reinterpret_cast<const short8*>(&Bbuf[db][e * 32 + psrc * 8]);
    }
#pragma unroll
    for (int j = 0; j < 4; ++j) {
      acc2[0][j] = __builtin_amdgcn_mfma_f32_16x16x32_bf16(a0, bv[j], acc2[0][j], 0, 0, 0);
      acc2[1][j] = __builtin_amdgcn_mfma_f32_16x16x32_bf16(a1, bv[j], acc2[1][j], 0, 0, 0);
    }
    __syncthreads();
  }

  // write R into PBuf (all attn reads done at last barrier)
#pragma unroll
  for (int i = 0; i < 2; ++i)
#pragma unroll
    for (int r = 0; r < 4; ++r) {
      int row = i * 16 + grp * 4 + r;
#pragma unroll
      for (int j = 0; j < 4; ++j)
        PBuf[row * PST + w * 64 + j * 16 + lr] = f2bf(acc2[i][j][r]);
    }
  __syncthreads();

  // ---------- phase 4: out = R · wv_h^T + bv_h  (M=32, N=64, K=512) ----------
  int wr = w >> 2, wc = w & 3;
  f32x4 acc3 = (f32x4)(0.0f);
  const ushort* wvh = wvb + (long)(h * 64 + wc * 16) * EMB;
#pragma unroll
  for (int c = 0; c < 16; ++c) {
    short8 a = *reinterpret_cast<const short8*>(&PBuf[(wr * 16 + lr) * PST + c * 32 + koU]);
    short8 b = *reinterpret_cast<const short8*>(wvh + (long)lr * EMB + c * 32 + koU);
    acc3 = __builtin_amdgcn_mfma_f32_16x16x32_bf16(a, b, acc3, 0, 0, 0);
  }
  float bias = bvb[h * 64 + wc * 16 + lr];
#pragma unroll
  for (int r = 0; r < 4; ++r) {
    int row = wr * 16 + grp * 4 + r;
    aout[(long)(g * 32 + row) * EMB + h * 64 + wc * 16 + lr] = f2bf(acc3[r] + bias);
  }
}

// ---- generic C = A·B^T (+bias) GEMM (out_proj only) ----
template <int FM, int FN, int WM, int WN, bool OUT_BF16, bool HAS_BIAS>
__global__ void gemm_abt(const ushort* __restrict__ A, const ushort* __restrict__ Bm,
                         void* __restrict__ C, const float* __restrict__ bias,
                         int K, int lda, int ldb, int ldc) {
  int tid = threadIdx.x;
  int wave = tid >> 6, lane = tid & 63;
  int wr = wave / WN, wc = wave % WN;
  int rowBase = blockIdx.y * (WM * FM * 16) + wr * FM * 16;
  int colBase = blockIdx.x * (WN * FN * 16) + wc * FN * 16;
  int lr = lane & 15;
  int ko = (lane >> 4) * 8;

  f32x4 acc[FM][FN];
#pragma unroll
  for (int i = 0; i < FM; ++i)
#pragma unroll
    for (int j = 0; j < FN; ++j) acc[i][j] = (f32x4)(0.0f);

  for (int kk = 0; kk < K; kk += 32) {
    short8 av[FM], bv[FN];
#pragma unroll
    for (int i = 0; i < FM; ++i)
      av[i] = *reinterpret_cast<const short8*>(A + (long)(rowBase + i * 16 + lr) * lda + kk + ko);
#pragma unroll
    for (int j = 0; j < FN; ++j)
      bv[j] = *reinterpret_cast<const short8*>(Bm + (long)(colBase + j * 16 + lr) * ldb + kk + ko);
#pragma unroll
    for (int i = 0; i < FM; ++i)
#pragma unroll
      for (int j = 0; j < FN; ++j)
        acc[i][j] = __builtin_amdgcn_mfma_f32_16x16x32_bf16(av[i], bv[j], acc[i][j], 0, 0, 0);
  }

  int or0 = (lane >> 4) * 4;
#pragma unroll
  for (int i = 0; i < FM; ++i) {
#pragma unroll
    for (int j = 0; j < FN; ++j) {
      int col = colBase + j * 16 + lr;
      float bval = HAS_BIAS ? bias[col] : 0.f;
#pragma unroll
      for (int r = 0; r < 4; ++r) {
        int row = rowBase + i * 16 + or0 + r;
        float v = acc[i][j][r] + bval;
        if (OUT_BF16)
          ((ushort*)C)[(long)row * ldc + col] = f2bf(v);
        else
          ((float*)C)[(long)row * ldc + col] = v;
      }
    }
  }
}

extern "C" void kernel_launch(void* const* d_in, const int* in_sizes, int n_in,
                              void* d_out, int out_size, void* d_ws, size_t ws_size,
                              hipStream_t stream) {
  const float* x          = (const float*)d_in[0];
  const float* xcent_base = (const float*)d_in[3];
  const float* in_proj_w  = (const float*)d_in[4];
  const float* in_proj_b  = (const float*)d_in[5];
  const float* out_proj_w = (const float*)d_in[6];
  const float* out_proj_b = (const float*)d_in[7];

  char* w = (char*)d_ws;
  ushort* xb   = (ushort*)(w);                 // 16 MiB
  ushort* xbT  = (ushort*)(w + 16777216);      // 16 MiB
  ushort* PCb  = (ushort*)(w + 33554432);      // 256 KiB
  ushort* wvb  = (ushort*)(w + 33816576);      // 512 KiB
  ushort* wob  = (ushort*)(w + 34340864);      // 512 KiB
  ushort* aout = (ushort*)(w + 34865152);      // 1 MiB

  const float* wq = in_proj_w;
  const float* wk = in_proj_w + 512 * 512;
  const float* wv = in_proj_w + 1024 * 512;
  const float* bq = in_proj_b;
  const float* bv = in_proj_b + 1024;

  prep_x<<<dim3(EMB / 32, NNODES / 32), 256, 0, stream>>>(x, xb, xbT);
  prep_w<<<513, 256, 0, stream>>>(wv, out_proj_w, wvb, wob, (float*)d_out + LQ * EMB);
  qpc<<<64, 256, 0, stream>>>(xcent_base, wq, bq, wk, PCb);

  fused_attn<<<256, 512, 0, stream>>>(PCb, xb, xbT, wvb, bv, aout);

  // out_proj: xcent[1024,512] = aout · wo^T + bo  (f32 -> d_out), 32x64 tiles, 256 blocks
  gemm_abt<1, 2, 2, 2, false, true><<<dim3(8, 32, 1), 256, 0, stream>>>(
      aout, wob, d_out, out_proj_b, 512, 512, 512, 512);
}

// Round 4
// 73.776 us; speedup vs baseline: 2.8563x; 2.8563x over previous
//
#include <hip/hip_runtime.h>
#include <hip/hip_bf16.h>

#define NGRAPH 32
#define NHEAD 8
#define EMB 512
#define NNODES 16384
#define NPG 512
#define LQ 1024
#define PST 520   // padded LDS row stride (ushorts): 2-way bank aliasing (free)

typedef __attribute__((ext_vector_type(8))) short short8;
typedef __attribute__((ext_vector_type(4))) float f32x4;

static __device__ __forceinline__ unsigned short f2bf(float f) {
  union { float f; unsigned u; } v; v.f = f;
  unsigned r = (v.u + 0x7fffu + ((v.u >> 16) & 1u)) >> 16;
  return (unsigned short)r;
}

// async global->LDS, 16B per lane; LDS dest = wave-uniform base + lane*16
static __device__ __forceinline__ void gload_lds16(const ushort* g, ushort* l) {
  __builtin_amdgcn_global_load_lds(
      (const __attribute__((address_space(1))) unsigned*)g,
      (__attribute__((address_space(3))) unsigned*)l, 16, 0, 0);
}

// ---- x [N,E] f32 -> xb [N,E] bf16 AND xbT [E,N] bf16 (one read of x) ----
__global__ void prep_x(const float* __restrict__ x, ushort* __restrict__ xb,
                       ushort* __restrict__ xbT) {
  __shared__ ushort tile[32][33];
  int bc = blockIdx.x;   // E/32
  int br = blockIdx.y;   // N/32
  int t = threadIdx.x, lr = t >> 5, lc = t & 31;
#pragma unroll
  for (int p = 0; p < 4; ++p) {
    int r = lr + p * 8;
    long gi = (long)(br * 32 + r) * EMB + bc * 32 + lc;
    ushort b = f2bf(x[gi]);
    xb[gi] = b;
    tile[r][lc] = b;
  }
  __syncthreads();
#pragma unroll
  for (int p = 0; p < 4; ++p) {
    int r = lr + p * 8;
    xbT[(long)(bc * 32 + r) * NNODES + br * 32 + lc] = tile[lc][r];
  }
}

// ---- weight/seed conversions f32 -> bf16 + batchcent ----
// blocks: [0,256) wv ; [256,512) wo ; [512,768) wq ; [768,784) xcent ; 784 batchcent
__global__ void prep_w(const float* __restrict__ wv, const float* __restrict__ wo,
                       const float* __restrict__ wq, const float* __restrict__ xc,
                       ushort* __restrict__ wvb, ushort* __restrict__ wob,
                       ushort* __restrict__ wqb, ushort* __restrict__ xcb,
                       float* __restrict__ bcent) {
  int b = blockIdx.x;
  if (b == 784) {
    int i = threadIdx.x;
#pragma unroll
    for (int p = 0; p < 4; ++p) bcent[i + p * 256] = (float)((i + p * 256) >> 5);
    return;
  }
  const float* src; ushort* dst; int off;
  if (b < 256)       { src = wv; dst = wvb; off = b; }
  else if (b < 512)  { src = wo; dst = wob; off = b - 256; }
  else if (b < 768)  { src = wq; dst = wqb; off = b - 512; }
  else               { src = xc; dst = xcb; off = b - 768; }
  int i = (off * 256 + threadIdx.x) * 4;
  float4 v = *reinterpret_cast<const float4*>(src + i);
  ushort4 o;
  o.x = f2bf(v.x); o.y = f2bf(v.y); o.z = f2bf(v.z); o.w = f2bf(v.w);
  *reinterpret_cast<ushort4*>(dst + i) = o;
}

// ---- wk [d,k] f32 -> wkT [k,d] bf16, scaled by 1/sqrt(64) ----
__global__ void prep_wkT(const float* __restrict__ wk, ushort* __restrict__ wkT) {
  __shared__ ushort tile[32][33];
  int bd = blockIdx.x, bk = blockIdx.y;
  int t = threadIdx.x, lr = t >> 5, lc = t & 31;
#pragma unroll
  for (int p = 0; p < 4; ++p) {
    int r = lr + p * 8;
    tile[r][lc] = f2bf(0.125f * wk[(long)(bd * 32 + r) * EMB + bk * 32 + lc]);
  }
  __syncthreads();
#pragma unroll
  for (int p = 0; p < 4; ++p) {
    int r = lr + p * 8;
    wkT[(long)(bk * 32 + r) * EMB + bd * 32 + lc] = tile[lc][r];
  }
}

// ---- per-head MFMA: Q_h = xcb·wq_h^T + bq_h (LDS), then PC_h = Q_h·wkT_h ----
// grid = 8 (one block per head), 256 threads = 4 waves.
__global__ __launch_bounds__(256) void qpc_mfma(
    const ushort* __restrict__ xcb, const ushort* __restrict__ wqb,
    const float* __restrict__ bq, const ushort* __restrict__ wkTb,
    ushort* __restrict__ PCb) {
  __shared__ ushort Qs[32][72];   // Q_h bf16, pad 64->72 (stride 144B, 2-way free)
  int h = blockIdx.x;
  int t = threadIdx.x, w = t >> 6, lane = t & 63;
  int lr = lane & 15, grp = lane >> 4, ko = grp * 8;

  // phase A: Q_h[32,64] = xcb[32,512] · wq_h[64,512]^T + bq_h ; wave w -> cols w*16..+16
  f32x4 qa[2];
  qa[0] = (f32x4)(0.0f); qa[1] = (f32x4)(0.0f);
  for (int kk = 0; kk < EMB; kk += 32) {
    short8 a0 = *reinterpret_cast<const short8*>(xcb + lr * EMB + kk + ko);
    short8 a1 = *reinterpret_cast<const short8*>(xcb + (16 + lr) * EMB + kk + ko);
    short8 b  = *reinterpret_cast<const short8*>(wqb + (long)(h * 64 + w * 16 + lr) * EMB + kk + ko);
    qa[0] = __builtin_amdgcn_mfma_f32_16x16x32_bf16(a0, b, qa[0], 0, 0, 0);
    qa[1] = __builtin_amdgcn_mfma_f32_16x16x32_bf16(a1, b, qa[1], 0, 0, 0);
  }
  float bias = bq[h * 64 + w * 16 + lr];
#pragma unroll
  for (int i = 0; i < 2; ++i)
#pragma unroll
    for (int r = 0; r < 4; ++r)
      Qs[i * 16 + grp * 4 + r][w * 16 + lr] = f2bf(qa[i][r] + bias);
  __syncthreads();

  // phase B: PC_h[32,512] = Q_h[32,64] · wkT_h^T  (B rows n=k from wkTb, K=64)
  f32x4 pa[2][8];
#pragma unroll
  for (int i = 0; i < 2; ++i)
#pragma unroll
    for (int j = 0; j < 8; ++j) pa[i][j] = (f32x4)(0.0f);
  for (int kk = 0; kk < 64; kk += 32) {
    short8 a0 = *reinterpret_cast<const short8*>(&Qs[lr][kk + ko]);
    short8 a1 = *reinterpret_cast<const short8*>(&Qs[16 + lr][kk + ko]);
#pragma unroll
    for (int j = 0; j < 8; ++j) {
      short8 b = *reinterpret_cast<const short8*>(
          wkTb + (long)(w * 128 + j * 16 + lr) * EMB + h * 64 + kk + ko);
      pa[0][j] = __builtin_amdgcn_mfma_f32_16x16x32_bf16(a0, b, pa[0][j], 0, 0, 0);
      pa[1][j] = __builtin_amdgcn_mfma_f32_16x16x32_bf16(a1, b, pa[1][j], 0, 0, 0);
    }
  }
#pragma unroll
  for (int i = 0; i < 2; ++i)
#pragma unroll
    for (int j = 0; j < 8; ++j)
#pragma unroll
      for (int r = 0; r < 4; ++r)
        PCb[(long)(h * 32 + i * 16 + grp * 4 + r) * EMB + w * 128 + j * 16 + lr] =
            f2bf(pa[i][j][r]);
}

// ---- fused attention per (graph, head), 8 waves, LDS-staged, double-buffered ----
__global__ __launch_bounds__(512) void fused_attn(
    const ushort* __restrict__ PCb, const ushort* __restrict__ xb,
    const ushort* __restrict__ xbT, const ushort* __restrict__ wvb,
    const float* __restrict__ bvb, ushort* __restrict__ aout) {
  __shared__ ushort PCl[32 * PST];      // PC_h padded
  __shared__ ushort PBuf[32 * PST];     // attn, then R
  __shared__ ushort Bbuf[2][16384];     // double-buffered B chunk [512 rows][32 K]
  __shared__ float rmax[32][8];
  __shared__ float rsum[32][8];

  const int g = blockIdx.x & 31, h = blockIdx.x >> 5;
  const int t = threadIdx.x, w = t >> 6, lane = t & 63;
  const int lr = lane & 15, grp = lane >> 4;
  const int koU = grp * 8;

  const ushort* xg  = xb  + (long)g * NPG * EMB;
  const ushort* xTg = xbT + g * NPG;

  const int srow  = w * 16 + (lane >> 2);
  const int spart = lane & 3;

  auto STAGE1 = [&](int c, int db) {
#pragma unroll
    for (int q = 0; q < 4; ++q) {
      int row = q * 128 + srow;
      int psrc = spart ^ ((row >> 1) & 3);
      gload_lds16(xg + (long)row * EMB + c * 32 + psrc * 8,
                  &Bbuf[db][q * 4096 + w * 512]);
    }
  };
  auto STAGE3 = [&](int c, int db) {
#pragma unroll
    for (int q = 0; q < 4; ++q) {
      int row = q * 128 + srow;
      int psrc = spart ^ ((row >> 1) & 3);
      gload_lds16(xTg + (long)row * NNODES + c * 32 + psrc * 8,
                  &Bbuf[db][q * 4096 + w * 512]);
    }
  };

  STAGE1(0, 0);
  {
    const ushort* pc = PCb + h * 32 * EMB;
#pragma unroll
    for (int p = 0; p < 4; ++p) {
      int u = t + p * 512;
      int row = u >> 6, col = (u & 63) * 8;
      *reinterpret_cast<short8*>(&PCl[row * PST + col]) =
          *reinterpret_cast<const short8*>(pc + row * EMB + col);
    }
  }
  __syncthreads();

  // phase 1: S = PC_h · X_g^T
  f32x4 acc[2][4];
#pragma unroll
  for (int i = 0; i < 2; ++i)
#pragma unroll
    for (int j = 0; j < 4; ++j) acc[i][j] = (f32x4)(0.0f);

#pragma unroll
  for (int c = 0; c < 16; ++c) {
    int db = c & 1;
    if (c < 15) STAGE1(c + 1, db ^ 1);
    short8 a0 = *reinterpret_cast<const short8*>(&PCl[lr * PST + c * 32 + koU]);
    short8 a1 = *reinterpret_cast<const short8*>(&PCl[(16 + lr) * PST + c * 32 + koU]);
    short8 bv[4];
#pragma unroll
    for (int j = 0; j < 4; ++j) {
      int n = w * 64 + j * 16 + lr;
      int psrc = grp ^ ((n >> 1) & 3);
      bv[j] = *reinterpret_cast<const short8*>(&Bbuf[db][n * 32 + psrc * 8]);
    }
#pragma unroll
    for (int j = 0; j < 4; ++j) {
      acc[0][j] = __builtin_amdgcn_mfma_f32_16x16x32_bf16(a0, bv[j], acc[0][j], 0, 0, 0);
      acc[1][j] = __builtin_amdgcn_mfma_f32_16x16x32_bf16(a1, bv[j], acc[1][j], 0, 0, 0);
    }
    __syncthreads();
  }

  // phase 2: softmax
#pragma unroll
  for (int i = 0; i < 2; ++i)
#pragma unroll
    for (int r = 0; r < 4; ++r) {
      float m = fmaxf(fmaxf(acc[i][0][r], acc[i][1][r]), fmaxf(acc[i][2][r], acc[i][3][r]));
      m = fmaxf(m, __shfl_xor(m, 1)); m = fmaxf(m, __shfl_xor(m, 2));
      m = fmaxf(m, __shfl_xor(m, 4)); m = fmaxf(m, __shfl_xor(m, 8));
      if (lr == 0) rmax[i * 16 + grp * 4 + r][w] = m;
    }
  __syncthreads();
#pragma unroll
  for (int i = 0; i < 2; ++i)
#pragma unroll
    for (int r = 0; r < 4; ++r) {
      int row = i * 16 + grp * 4 + r;
      float m = rmax[row][0];
#pragma unroll
      for (int q = 1; q < 8; ++q) m = fmaxf(m, rmax[row][q]);
      float s = 0.f;
#pragma unroll
      for (int j = 0; j < 4; ++j) {
        float e = __expf(acc[i][j][r] - m);
        acc[i][j][r] = e;
        s += e;
      }
      s += __shfl_xor(s, 1); s += __shfl_xor(s, 2);
      s += __shfl_xor(s, 4); s += __shfl_xor(s, 8);
      if (lr == 0) rsum[row][w] = s;
    }
  __syncthreads();
#pragma unroll
  for (int i = 0; i < 2; ++i)
#pragma unroll
    for (int r = 0; r < 4; ++r) {
      int row = i * 16 + grp * 4 + r;
      float tot = rsum[row][0];
#pragma unroll
      for (int q = 1; q < 8; ++q) tot += rsum[row][q];
      float inv = 1.f / tot;
#pragma unroll
      for (int j = 0; j < 4; ++j)
        PBuf[row * PST + w * 64 + j * 16 + lr] = f2bf(acc[i][j][r] * inv);
    }
  STAGE3(0, 0);
  __syncthreads();

  // phase 3: R = attn · X_g
  f32x4 acc2[2][4];
#pragma unroll
  for (int i = 0; i < 2; ++i)
#pragma unroll
    for (int j = 0; j < 4; ++j) acc2[i][j] = (f32x4)(0.0f);

#pragma unroll
  for (int c = 0; c < 16; ++c) {
    int db = c & 1;
    if (c < 15) STAGE3(c + 1, db ^ 1);
    short8 a0 = *reinterpret_cast<const short8*>(&PBuf[lr * PST + c * 32 + koU]);
    short8 a1 = *reinterpret_cast<const short8*>(&PBuf[(16 + lr) * PST + c * 32 + koU]);
    short8 bv[4];
#pragma unroll
    for (int j = 0; j < 4; ++j) {
      int e = w * 64 + j * 16 + lr;
      int psrc = grp ^ ((e >> 1) & 3);
      bv[j] = *reinterpret_cast<const short8*>(&Bbuf[db][e * 32 + psrc * 8]);
    }
#pragma unroll
    for (int j = 0; j < 4; ++j) {
      acc2[0][j] = __builtin_amdgcn_mfma_f32_16x16x32_bf16(a0, bv[j], acc2[0][j], 0, 0, 0);
      acc2[1][j] = __builtin_amdgcn_mfma_f32_16x16x32_bf16(a1, bv[j], acc2[1][j], 0, 0, 0);
    }
    __syncthreads();
  }

#pragma unroll
  for (int i = 0; i < 2; ++i)
#pragma unroll
    for (int r = 0; r < 4; ++r) {
      int row = i * 16 + grp * 4 + r;
#pragma unroll
      for (int j = 0; j < 4; ++j)
        PBuf[row * PST + w * 64 + j * 16 + lr] = f2bf(acc2[i][j][r]);
    }
  __syncthreads();

  // phase 4: out = R · wv_h^T + bv_h
  int wr = w >> 2, wc = w & 3;
  f32x4 acc3 = (f32x4)(0.0f);
  const ushort* wvh = wvb + (long)(h * 64 + wc * 16) * EMB;
#pragma unroll
  for (int c = 0; c < 16; ++c) {
    short8 a = *reinterpret_cast<const short8*>(&PBuf[(wr * 16 + lr) * PST + c * 32 + koU]);
    short8 b = *reinterpret_cast<const short8*>(wvh + (long)lr * EMB + c * 32 + koU);
    acc3 = __builtin_amdgcn_mfma_f32_16x16x32_bf16(a, b, acc3, 0, 0, 0);
  }
  float bias = bvb[h * 64 + wc * 16 + lr];
#pragma unroll
  for (int r = 0; r < 4; ++r) {
    int row = wr * 16 + grp * 4 + r;
    aout[(long)(g * 32 + row) * EMB + h * 64 + wc * 16 + lr] = f2bf(acc3[r] + bias);
  }
}

// ---- generic C = A·B^T (+bias) GEMM (out_proj only) ----
template <int FM, int FN, int WM, int WN, bool OUT_BF16, bool HAS_BIAS>
__global__ void gemm_abt(const ushort* __restrict__ A, const ushort* __restrict__ Bm,
                         void* __restrict__ C, const float* __restrict__ bias,
                         int K, int lda, int ldb, int ldc) {
  int tid = threadIdx.x;
  int wave = tid >> 6, lane = tid & 63;
  int wr = wave / WN, wc = wave % WN;
  int rowBase = blockIdx.y * (WM * FM * 16) + wr * FM * 16;
  int colBase = blockIdx.x * (WN * FN * 16) + wc * FN * 16;
  int lr = lane & 15;
  int ko = (lane >> 4) * 8;

  f32x4 acc[FM][FN];
#pragma unroll
  for (int i = 0; i < FM; ++i)
#pragma unroll
    for (int j = 0; j < FN; ++j) acc[i][j] = (f32x4)(0.0f);

  for (int kk = 0; kk < K; kk += 32) {
    short8 av[FM], bv[FN];
#pragma unroll
    for (int i = 0; i < FM; ++i)
      av[i] = *reinterpret_cast<const short8*>(A + (long)(rowBase + i * 16 + lr) * lda + kk + ko);
#pragma unroll
    for (int j = 0; j < FN; ++j)
      bv[j] = *reinterpret_cast<const short8*>(Bm + (long)(colBase + j * 16 + lr) * ldb + kk + ko);
#pragma unroll
    for (int i = 0; i < FM; ++i)
#pragma unroll
      for (int j = 0; j < FN; ++j)
        acc[i][j] = __builtin_amdgcn_mfma_f32_16x16x32_bf16(av[i], bv[j], acc[i][j], 0, 0, 0);
  }

  int or0 = (lane >> 4) * 4;
#pragma unroll
  for (int i = 0; i < FM; ++i) {
#pragma unroll
    for (int j = 0; j < FN; ++j) {
      int col = colBase + j * 16 + lr;
      float bval = HAS_BIAS ? bias[col] : 0.f;
#pragma unroll
      for (int r = 0; r < 4; ++r) {
        int row = rowBase + i * 16 + or0 + r;
        float v = acc[i][j][r] + bval;
        if (OUT_BF16)
          ((ushort*)C)[(long)row * ldc + col] = f2bf(v);
        else
          ((float*)C)[(long)row * ldc + col] = v;
      }
    }
  }
}

extern "C" void kernel_launch(void* const* d_in, const int* in_sizes, int n_in,
                              void* d_out, int out_size, void* d_ws, size_t ws_size,
                              hipStream_t stream) {
  const float* x          = (const float*)d_in[0];
  const float* xcent_base = (const float*)d_in[3];
  const float* in_proj_w  = (const float*)d_in[4];
  const float* in_proj_b  = (const float*)d_in[5];
  const float* out_proj_w = (const float*)d_in[6];
  const float* out_proj_b = (const float*)d_in[7];

  char* w = (char*)d_ws;
  ushort* xb   = (ushort*)(w);                 // 16 MiB
  ushort* xbT  = (ushort*)(w + 16777216);      // 16 MiB
  ushort* PCb  = (ushort*)(w + 33554432);      // 256 KiB
  ushort* wvb  = (ushort*)(w + 33816576);      // 512 KiB
  ushort* wob  = (ushort*)(w + 34340864);      // 512 KiB
  ushort* wqb  = (ushort*)(w + 34865152);      // 512 KiB
  ushort* wkTb = (ushort*)(w + 35389440);      // 512 KiB
  ushort* xcb  = (ushort*)(w + 35913728);      // 32 KiB
  ushort* aout = (ushort*)(w + 35946496);      // 1 MiB

  const float* wq = in_proj_w;
  const float* wk = in_proj_w + 512 * 512;
  const float* wv = in_proj_w + 1024 * 512;
  const float* bq = in_proj_b;
  const float* bv = in_proj_b + 1024;

  prep_x<<<dim3(EMB / 32, NNODES / 32), 256, 0, stream>>>(x, xb, xbT);
  prep_w<<<785, 256, 0, stream>>>(wv, out_proj_w, wq, xcent_base,
                                  wvb, wob, wqb, xcb, (float*)d_out + LQ * EMB);
  prep_wkT<<<dim3(16, 16), 256, 0, stream>>>(wk, wkTb);
  qpc_mfma<<<8, 256, 0, stream>>>(xcb, wqb, bq, wkTb, PCb);

  fused_attn<<<256, 512, 0, stream>>>(PCb, xb, xbT, wvb, bv, aout);

  gemm_abt<1, 2, 2, 2, false, true><<<dim3(8, 32, 1), 256, 0, stream>>>(
      aout, wob, d_out, out_proj_b, 512, 512, 512, 512);
}

// Round 5
// 65.600 us; speedup vs baseline: 3.2123x; 1.1246x over previous
//
#include <hip/hip_runtime.h>
#include <hip/hip_bf16.h>

#define NGRAPH 32
#define NHEAD 8
#define EMB 512
#define NNODES 16384
#define NPG 512
#define LQ 1024
#define PST 520   // padded LDS row stride (ushorts): 2-way bank aliasing (free)

typedef __attribute__((ext_vector_type(8))) short short8;
typedef __attribute__((ext_vector_type(4))) float f32x4;

static __device__ __forceinline__ unsigned short f2bf(float f) {
  union { float f; unsigned u; } v; v.f = f;
  unsigned r = (v.u + 0x7fffu + ((v.u >> 16) & 1u)) >> 16;
  return (unsigned short)r;
}

static __device__ __forceinline__ void gload_lds16(const ushort* g, ushort* l) {
  __builtin_amdgcn_global_load_lds(
      (const __attribute__((address_space(1))) unsigned*)g,
      (__attribute__((address_space(3))) unsigned*)l, 16, 0, 0);
}

// lgkm-only barrier: does NOT drain vmcnt -> global_load_lds prefetches survive
#define BARRIER_LGKM()                                        \
  do {                                                        \
    asm volatile("s_waitcnt lgkmcnt(0)" ::: "memory");        \
    __builtin_amdgcn_s_barrier();                             \
  } while (0)

// ---- x [N,E] f32 -> xb [N,E] bf16 AND xbT [E,N] bf16 (one read of x) ----
__global__ void prep_x(const float* __restrict__ x, ushort* __restrict__ xb,
                       ushort* __restrict__ xbT) {
  __shared__ ushort tile[32][33];
  int bc = blockIdx.x;   // E/32
  int br = blockIdx.y;   // N/32
  int t = threadIdx.x, lr = t >> 5, lc = t & 31;
#pragma unroll
  for (int p = 0; p < 4; ++p) {
    int r = lr + p * 8;
    long gi = (long)(br * 32 + r) * EMB + bc * 32 + lc;
    ushort b = f2bf(x[gi]);
    xb[gi] = b;
    tile[r][lc] = b;
  }
  __syncthreads();
#pragma unroll
  for (int p = 0; p < 4; ++p) {
    int r = lr + p * 8;
    xbT[(long)(bc * 32 + r) * NNODES + br * 32 + lc] = tile[lc][r];
  }
}

// ---- weight/seed conversions f32 -> bf16 + batchcent ----
__global__ void prep_w(const float* __restrict__ wv, const float* __restrict__ wo,
                       const float* __restrict__ wq, const float* __restrict__ xc,
                       ushort* __restrict__ wvb, ushort* __restrict__ wob,
                       ushort* __restrict__ wqb, ushort* __restrict__ xcb,
                       float* __restrict__ bcent) {
  int b = blockIdx.x;
  if (b == 784) {
    int i = threadIdx.x;
#pragma unroll
    for (int p = 0; p < 4; ++p) bcent[i + p * 256] = (float)((i + p * 256) >> 5);
    return;
  }
  const float* src; ushort* dst; int off;
  if (b < 256)       { src = wv; dst = wvb; off = b; }
  else if (b < 512)  { src = wo; dst = wob; off = b - 256; }
  else if (b < 768)  { src = wq; dst = wqb; off = b - 512; }
  else               { src = xc; dst = xcb; off = b - 768; }
  int i = (off * 256 + threadIdx.x) * 4;
  float4 v = *reinterpret_cast<const float4*>(src + i);
  ushort4 o;
  o.x = f2bf(v.x); o.y = f2bf(v.y); o.z = f2bf(v.z); o.w = f2bf(v.w);
  *reinterpret_cast<ushort4*>(dst + i) = o;
}

// ---- wk [d,k] f32 -> wkT [k,d] bf16, scaled by 1/sqrt(64) ----
__global__ void prep_wkT(const float* __restrict__ wk, ushort* __restrict__ wkT) {
  __shared__ ushort tile[32][33];
  int bd = blockIdx.x, bk = blockIdx.y;
  int t = threadIdx.x, lr = t >> 5, lc = t & 31;
#pragma unroll
  for (int p = 0; p < 4; ++p) {
    int r = lr + p * 8;
    tile[r][lc] = f2bf(0.125f * wk[(long)(bd * 32 + r) * EMB + bk * 32 + lc]);
  }
  __syncthreads();
#pragma unroll
  for (int p = 0; p < 4; ++p) {
    int r = lr + p * 8;
    wkT[(long)(bk * 32 + r) * EMB + bd * 32 + lc] = tile[lc][r];
  }
}

// ---- per-(head, col-quarter) MFMA: Q_h then PC_h col slice ----
// grid = 32: h = b>>2, qs = b&3 -> cols qs*128..+128
__global__ __launch_bounds__(256) void qpc_mfma(
    const ushort* __restrict__ xcb, const ushort* __restrict__ wqb,
    const float* __restrict__ bq, const ushort* __restrict__ wkTb,
    ushort* __restrict__ PCb) {
  __shared__ ushort Qs[32][72];
  int h = blockIdx.x >> 2, qs = blockIdx.x & 3;
  int t = threadIdx.x, w = t >> 6, lane = t & 63;
  int lr = lane & 15, grp = lane >> 4, ko = grp * 8;

  // phase A: Q_h[32,64] = xcb[32,512] · wq_h[64,512]^T + bq_h
  f32x4 qa[2];
  qa[0] = (f32x4)(0.0f); qa[1] = (f32x4)(0.0f);
#pragma unroll 4
  for (int kk = 0; kk < EMB; kk += 32) {
    short8 a0 = *reinterpret_cast<const short8*>(xcb + lr * EMB + kk + ko);
    short8 a1 = *reinterpret_cast<const short8*>(xcb + (16 + lr) * EMB + kk + ko);
    short8 b  = *reinterpret_cast<const short8*>(wqb + (long)(h * 64 + w * 16 + lr) * EMB + kk + ko);
    qa[0] = __builtin_amdgcn_mfma_f32_16x16x32_bf16(a0, b, qa[0], 0, 0, 0);
    qa[1] = __builtin_amdgcn_mfma_f32_16x16x32_bf16(a1, b, qa[1], 0, 0, 0);
  }
  float bias = bq[h * 64 + w * 16 + lr];
#pragma unroll
  for (int i = 0; i < 2; ++i)
#pragma unroll
    for (int r = 0; r < 4; ++r)
      Qs[i * 16 + grp * 4 + r][w * 16 + lr] = f2bf(qa[i][r] + bias);
  __syncthreads();

  // phase B: PC_h[32, qs*128..+128] = Q_h · wkT_h^T  (K=64)
  f32x4 pa[2][2];
#pragma unroll
  for (int i = 0; i < 2; ++i)
#pragma unroll
    for (int j = 0; j < 2; ++j) pa[i][j] = (f32x4)(0.0f);
#pragma unroll
  for (int kk = 0; kk < 64; kk += 32) {
    short8 a0 = *reinterpret_cast<const short8*>(&Qs[lr][kk + ko]);
    short8 a1 = *reinterpret_cast<const short8*>(&Qs[16 + lr][kk + ko]);
#pragma unroll
    for (int j = 0; j < 2; ++j) {
      short8 b = *reinterpret_cast<const short8*>(
          wkTb + (long)(qs * 128 + w * 32 + j * 16 + lr) * EMB + h * 64 + kk + ko);
      pa[0][j] = __builtin_amdgcn_mfma_f32_16x16x32_bf16(a0, b, pa[0][j], 0, 0, 0);
      pa[1][j] = __builtin_amdgcn_mfma_f32_16x16x32_bf16(a1, b, pa[1][j], 0, 0, 0);
    }
  }
#pragma unroll
  for (int i = 0; i < 2; ++i)
#pragma unroll
    for (int j = 0; j < 2; ++j)
#pragma unroll
      for (int r = 0; r < 4; ++r)
        PCb[(long)(h * 32 + i * 16 + grp * 4 + r) * EMB + qs * 128 + w * 32 + j * 16 + lr] =
            f2bf(pa[i][j][r]);
}

// ---- fused attention per (graph, head): barrier-free K-loops, counted vmcnt ----
// Wave-private B slices: wave w stages AND reads only rows w*64..w*64+64 of Bbuf.
__global__ __launch_bounds__(512, 2) void fused_attn(
    const ushort* __restrict__ PCb, const ushort* __restrict__ xb,
    const ushort* __restrict__ xbT, const ushort* __restrict__ wvb,
    const float* __restrict__ bvb, ushort* __restrict__ aout) {
  __shared__ ushort PCl[32 * PST];
  __shared__ ushort PBuf[32 * PST];
  __shared__ ushort Bbuf[2][16384];   // [buf][512 rows][32 K] ushorts
  __shared__ float rmax[32][8];
  __shared__ float rsum[32][8];

  const int g = blockIdx.x & 31, h = blockIdx.x >> 5;  // g%8 == blk%8 -> XCD pinning
  const int t = threadIdx.x, w = t >> 6, lane = t & 63;
  const int lr = lane & 15, grp = lane >> 4;
  const int koU = grp * 8;

  const ushort* xg  = xb  + (long)g * NPG * EMB;
  const ushort* xTg = xbT + g * NPG;

  // wave-private staging: wave w covers rows w*64..w*64+64, 4 calls of 16 rows
  const int srow0 = w * 64 + (lane >> 2);   // + q*16
  const int spart = lane & 3;

  auto STAGE1 = [&](int c, int db) {
#pragma unroll
    for (int q = 0; q < 4; ++q) {
      int row = srow0 + q * 16;
      int psrc = spart ^ ((row >> 1) & 3);
      gload_lds16(xg + (long)row * EMB + c * 32 + psrc * 8,
                  &Bbuf[db][(w * 64 + q * 16) * 32]);
    }
  };
  auto STAGE3 = [&](int c, int db) {
#pragma unroll
    for (int q = 0; q < 4; ++q) {
      int row = srow0 + q * 16;
      int psrc = spart ^ ((row >> 1) & 3);
      gload_lds16(xTg + (long)row * NNODES + c * 32 + psrc * 8,
                  &Bbuf[db][(w * 64 + q * 16) * 32]);
    }
  };

  STAGE1(0, 0);
  STAGE1(1, 1);
  // stage PC_h into padded LDS (reg-staged; compiler inserts its own waits)
  {
    const ushort* pc = PCb + h * 32 * EMB;
#pragma unroll
    for (int p = 0; p < 4; ++p) {
      int u = t + p * 512;
      int row = u >> 6, col = (u & 63) * 8;
      *reinterpret_cast<short8*>(&PCl[row * PST + col]) =
          *reinterpret_cast<const short8*>(pc + row * EMB + col);
    }
  }
  BARRIER_LGKM();   // PCl visible to all waves

  // ---------- phase 1: S = PC_h · X_g^T ; K-loop, NO barriers ----------
  f32x4 acc[2][4];
#pragma unroll
  for (int i = 0; i < 2; ++i)
#pragma unroll
    for (int j = 0; j < 4; ++j) acc[i][j] = (f32x4)(0.0f);

#pragma unroll
  for (int c = 0; c < 16; ++c) {
    const int db = c & 1;
    asm volatile("s_waitcnt vmcnt(4)" ::: "memory");   // chunk c landed; c+1 in flight
    __builtin_amdgcn_sched_barrier(0);
    short8 a0 = *reinterpret_cast<const short8*>(&PCl[lr * PST + c * 32 + koU]);
    short8 a1 = *reinterpret_cast<const short8*>(&PCl[(16 + lr) * PST + c * 32 + koU]);
    short8 bv[4];
#pragma unroll
    for (int j = 0; j < 4; ++j) {
      int n = w * 64 + j * 16 + lr;
      int psrc = grp ^ ((n >> 1) & 3);
      bv[j] = *reinterpret_cast<const short8*>(&Bbuf[db][n * 32 + psrc * 8]);
    }
#pragma unroll
    for (int j = 0; j < 4; ++j) {
      acc[0][j] = __builtin_amdgcn_mfma_f32_16x16x32_bf16(a0, bv[j], acc[0][j], 0, 0, 0);
      acc[1][j] = __builtin_amdgcn_mfma_f32_16x16x32_bf16(a1, bv[j], acc[1][j], 0, 0, 0);
    }
    __builtin_amdgcn_sched_barrier(0);                 // keep stage AFTER the reads
    if (c < 14) STAGE1(c + 2, db);
    else        STAGE3(c - 14, db);                    // prefetch phase-3 chunks 0,1
  }

  // ---------- phase 2: softmax (cols split 8 ways; raw barriers, vmcnt rides) ----------
#pragma unroll
  for (int i = 0; i < 2; ++i)
#pragma unroll
    for (int r = 0; r < 4; ++r) {
      float m = fmaxf(fmaxf(acc[i][0][r], acc[i][1][r]), fmaxf(acc[i][2][r], acc[i][3][r]));
      m = fmaxf(m, __shfl_xor(m, 1)); m = fmaxf(m, __shfl_xor(m, 2));
      m = fmaxf(m, __shfl_xor(m, 4)); m = fmaxf(m, __shfl_xor(m, 8));
      if (lr == 0) rmax[i * 16 + grp * 4 + r][w] = m;
    }
  BARRIER_LGKM();
#pragma unroll
  for (int i = 0; i < 2; ++i)
#pragma unroll
    for (int r = 0; r < 4; ++r) {
      int row = i * 16 + grp * 4 + r;
      float m = rmax[row][0];
#pragma unroll
      for (int q = 1; q < 8; ++q) m = fmaxf(m, rmax[row][q]);
      float s = 0.f;
#pragma unroll
      for (int j = 0; j < 4; ++j) {
        float e = __expf(acc[i][j][r] - m);
        acc[i][j][r] = e;
        s += e;
      }
      s += __shfl_xor(s, 1); s += __shfl_xor(s, 2);
      s += __shfl_xor(s, 4); s += __shfl_xor(s, 8);
      if (lr == 0) rsum[row][w] = s;
    }
  BARRIER_LGKM();
#pragma unroll
  for (int i = 0; i < 2; ++i)
#pragma unroll
    for (int r = 0; r < 4; ++r) {
      int row = i * 16 + grp * 4 + r;
      float tot = rsum[row][0];
#pragma unroll
      for (int q = 1; q < 8; ++q) tot += rsum[row][q];
      float inv = 1.f / tot;
#pragma unroll
      for (int j = 0; j < 4; ++j)
        PBuf[row * PST + w * 64 + j * 16 + lr] = f2bf(acc[i][j][r] * inv);
    }
  BARRIER_LGKM();   // attn ready in PBuf

  // ---------- phase 3: R = attn · X_g ; K-loop, NO barriers ----------
  f32x4 acc2[2][4];
#pragma unroll
  for (int i = 0; i < 2; ++i)
#pragma unroll
    for (int j = 0; j < 4; ++j) acc2[i][j] = (f32x4)(0.0f);

#pragma unroll
  for (int c = 0; c < 16; ++c) {
    const int db = c & 1;
    if (c < 15) asm volatile("s_waitcnt vmcnt(4)" ::: "memory");
    else        asm volatile("s_waitcnt vmcnt(0)" ::: "memory");
    __builtin_amdgcn_sched_barrier(0);
    short8 a0 = *reinterpret_cast<const short8*>(&PBuf[lr * PST + c * 32 + koU]);
    short8 a1 = *reinterpret_cast<const short8*>(&PBuf[(16 + lr) * PST + c * 32 + koU]);
    short8 bv[4];
#pragma unroll
    for (int j = 0; j < 4; ++j) {
      int e = w * 64 + j * 16 + lr;
      int psrc = grp ^ ((e >> 1) & 3);
      bv[j] = *reinterpret_cast<const short8*>(&Bbuf[db][e * 32 + psrc * 8]);
    }
#pragma unroll
    for (int j = 0; j < 4; ++j) {
      acc2[0][j] = __builtin_amdgcn_mfma_f32_16x16x32_bf16(a0, bv[j], acc2[0][j], 0, 0, 0);
      acc2[1][j] = __builtin_amdgcn_mfma_f32_16x16x32_bf16(a1, bv[j], acc2[1][j], 0, 0, 0);
    }
    __builtin_amdgcn_sched_barrier(0);
    if (c < 14) STAGE3(c + 2, db);
  }
  BARRIER_LGKM();   // all waves done reading attn in PBuf

  // write R into PBuf
#pragma unroll
  for (int i = 0; i < 2; ++i)
#pragma unroll
    for (int r = 0; r < 4; ++r) {
      int row = i * 16 + grp * 4 + r;
#pragma unroll
      for (int j = 0; j < 4; ++j)
        PBuf[row * PST + w * 64 + j * 16 + lr] = f2bf(acc2[i][j][r]);
    }
  BARRIER_LGKM();   // R ready

  // ---------- phase 4: out = R · wv_h^T + bv_h ----------
  int wr = w >> 2, wc = w & 3;
  f32x4 acc3 = (f32x4)(0.0f);
  const ushort* wvh = wvb + (long)(h * 64 + wc * 16) * EMB;
#pragma unroll
  for (int c = 0; c < 16; ++c) {
    short8 a = *reinterpret_cast<const short8*>(&PBuf[(wr * 16 + lr) * PST + c * 32 + koU]);
    short8 b = *reinterpret_cast<const short8*>(wvh + (long)lr * EMB + c * 32 + koU);
    acc3 = __builtin_amdgcn_mfma_f32_16x16x32_bf16(a, b, acc3, 0, 0, 0);
  }
  float bias = bvb[h * 64 + wc * 16 + lr];
#pragma unroll
  for (int r = 0; r < 4; ++r) {
    int row = wr * 16 + grp * 4 + r;
    aout[(long)(g * 32 + row) * EMB + h * 64 + wc * 16 + lr] = f2bf(acc3[r] + bias);
  }
}

// ---- generic C = A·B^T (+bias) GEMM (out_proj only), K templated for unroll ----
template <int KK, int FM, int FN, int WM, int WN, bool OUT_BF16, bool HAS_BIAS>
__global__ void gemm_abt(const ushort* __restrict__ A, const ushort* __restrict__ Bm,
                         void* __restrict__ C, const float* __restrict__ bias,
                         int lda, int ldb, int ldc) {
  int tid = threadIdx.x;
  int wave = tid >> 6, lane = tid & 63;
  int wr = wave / WN, wc = wave % WN;
  int rowBase = blockIdx.y * (WM * FM * 16) + wr * FM * 16;
  int colBase = blockIdx.x * (WN * FN * 16) + wc * FN * 16;
  int lr = lane & 15;
  int ko = (lane >> 4) * 8;

  f32x4 acc[FM][FN];
#pragma unroll
  for (int i = 0; i < FM; ++i)
#pragma unroll
    for (int j = 0; j < FN; ++j) acc[i][j] = (f32x4)(0.0f);

#pragma unroll 4
  for (int kk = 0; kk < KK; kk += 32) {
    short8 av[FM], bv[FN];
#pragma unroll
    for (int i = 0; i < FM; ++i)
      av[i] = *reinterpret_cast<const short8*>(A + (long)(rowBase + i * 16 + lr) * lda + kk + ko);
#pragma unroll
    for (int j = 0; j < FN; ++j)
      bv[j] = *reinterpret_cast<const short8*>(Bm + (long)(colBase + j * 16 + lr) * ldb + kk + ko);
#pragma unroll
    for (int i = 0; i < FM; ++i)
#pragma unroll
      for (int j = 0; j < FN; ++j)
        acc[i][j] = __builtin_amdgcn_mfma_f32_16x16x32_bf16(av[i], bv[j], acc[i][j], 0, 0, 0);
  }

  int or0 = (lane >> 4) * 4;
#pragma unroll
  for (int i = 0; i < FM; ++i) {
#pragma unroll
    for (int j = 0; j < FN; ++j) {
      int col = colBase + j * 16 + lr;
      float bval = HAS_BIAS ? bias[col] : 0.f;
#pragma unroll
      for (int r = 0; r < 4; ++r) {
        int row = rowBase + i * 16 + or0 + r;
        float v = acc[i][j][r] + bval;
        if (OUT_BF16)
          ((ushort*)C)[(long)row * ldc + col] = f2bf(v);
        else
          ((float*)C)[(long)row * ldc + col] = v;
      }
    }
  }
}

extern "C" void kernel_launch(void* const* d_in, const int* in_sizes, int n_in,
                              void* d_out, int out_size, void* d_ws, size_t ws_size,
                              hipStream_t stream) {
  const float* x          = (const float*)d_in[0];
  const float* xcent_base = (const float*)d_in[3];
  const float* in_proj_w  = (const float*)d_in[4];
  const float* in_proj_b  = (const float*)d_in[5];
  const float* out_proj_w = (const float*)d_in[6];
  const float* out_proj_b = (const float*)d_in[7];

  char* w = (char*)d_ws;
  ushort* xb   = (ushort*)(w);                 // 16 MiB
  ushort* xbT  = (ushort*)(w + 16777216);      // 16 MiB
  ushort* PCb  = (ushort*)(w + 33554432);      // 256 KiB
  ushort* wvb  = (ushort*)(w + 33816576);      // 512 KiB
  ushort* wob  = (ushort*)(w + 34340864);      // 512 KiB
  ushort* wqb  = (ushort*)(w + 34865152);      // 512 KiB
  ushort* wkTb = (ushort*)(w + 35389440);      // 512 KiB
  ushort* xcb  = (ushort*)(w + 35913728);      // 32 KiB
  ushort* aout = (ushort*)(w + 35946496);      // 1 MiB

  const float* wq = in_proj_w;
  const float* wk = in_proj_w + 512 * 512;
  const float* wv = in_proj_w + 1024 * 512;
  const float* bq = in_proj_b;
  const float* bv = in_proj_b + 1024;

  prep_x<<<dim3(EMB / 32, NNODES / 32), 256, 0, stream>>>(x, xb, xbT);
  prep_w<<<785, 256, 0, stream>>>(wv, out_proj_w, wq, xcent_base,
                                  wvb, wob, wqb, xcb, (float*)d_out + LQ * EMB);
  prep_wkT<<<dim3(16, 16), 256, 0, stream>>>(wk, wkTb);
  qpc_mfma<<<32, 256, 0, stream>>>(xcb, wqb, bq, wkTb, PCb);

  fused_attn<<<256, 512, 0, stream>>>(PCb, xb, xbT, wvb, bv, aout);

  gemm_abt<512, 1, 2, 2, 2, false, true><<<dim3(8, 32, 1), 256, 0, stream>>>(
      aout, wob, d_out, out_proj_b, 512, 512, 512);
}

// Round 6
// 62.940 us; speedup vs baseline: 3.3480x; 1.0423x over previous
//
#include <hip/hip_runtime.h>
#include <hip/hip_bf16.h>

#define NGRAPH 32
#define NHEAD 8
#define EMB 512
#define NNODES 16384
#define NPG 512
#define LQ 1024
#define PST 520   // padded LDS row stride (ushorts): 2-way bank aliasing (free)

typedef __attribute__((ext_vector_type(8))) short short8;
typedef __attribute__((ext_vector_type(4))) float f32x4;

static __device__ __forceinline__ unsigned short f2bf(float f) {
  union { float f; unsigned u; } v; v.f = f;
  unsigned r = (v.u + 0x7fffu + ((v.u >> 16) & 1u)) >> 16;
  return (unsigned short)r;
}

static __device__ __forceinline__ void gload_lds16(const ushort* g, ushort* l) {
  __builtin_amdgcn_global_load_lds(
      (const __attribute__((address_space(1))) unsigned*)g,
      (__attribute__((address_space(3))) unsigned*)l, 16, 0, 0);
}

// lgkm-only barrier: does NOT drain vmcnt -> global_load_lds prefetches survive
#define BARRIER_LGKM()                                        \
  do {                                                        \
    asm volatile("s_waitcnt lgkmcnt(0)" ::: "memory");        \
    __builtin_amdgcn_s_barrier();                             \
  } while (0)

// ---- x [N,E] f32 -> xb bf16 + xbT bf16. 64x64 tiles, wide stores.
// Block swizzle: flat id ≡ g (mod 8) so graph g's lines land in XCD g%8's L2,
// matching fused_attn's consumer mapping (block h*32+g -> XCD g%8).
__global__ __launch_bounds__(256) void prep_x(const float* __restrict__ x,
                                              ushort* __restrict__ xb,
                                              ushort* __restrict__ xbT) {
  __shared__ ushort tile[64][68];
  int id = blockIdx.x;            // 2048
  int xr = id & 7, j = id >> 3;   // j 0..255
  int m = j >> 6, r = j & 63;
  int g = xr + 8 * m;             // graph 0..31, = id%8 + 8m
  int bc = r & 7;                 // e-tile 0..7
  int br = g * 8 + (r >> 3);      // n-tile 0..255 (within graph g)
  int t = threadIdx.x;
  int trr = t >> 4, tc = t & 15;
#pragma unroll
  for (int p = 0; p < 4; ++p) {
    int n = trr + p * 16;
    long gi = (long)(br * 64 + n) * EMB + bc * 64 + tc * 4;
    float4 v = *reinterpret_cast<const float4*>(x + gi);
    ushort4 o;
    o.x = f2bf(v.x); o.y = f2bf(v.y); o.z = f2bf(v.z); o.w = f2bf(v.w);
    *reinterpret_cast<ushort4*>(xb + gi) = o;
    *reinterpret_cast<ushort4*>(&tile[n][tc * 4]) = o;
  }
  __syncthreads();
#pragma unroll
  for (int p = 0; p < 4; ++p) {
    int e = trr + p * 16;
    int n0 = tc * 4;
    ushort4 o;
    o.x = tile[n0][e]; o.y = tile[n0 + 1][e];
    o.z = tile[n0 + 2][e]; o.w = tile[n0 + 3][e];
    *reinterpret_cast<ushort4*>(xbT + (long)(bc * 64 + e) * NNODES + br * 64 + n0) = o;
  }
}

// ---- all weight prep in one launch ----
// [0,256) wv->wvb ; [256,512) wo->wob ; [512,768) wq->wqb ; [768,784) xc->xcb ;
// 784 batchcent ; [785,1041) wkT tiles (scale 0.125, transpose)
__global__ void prep_wb(const float* __restrict__ wv, const float* __restrict__ wo,
                        const float* __restrict__ wq, const float* __restrict__ xc,
                        const float* __restrict__ wk,
                        ushort* __restrict__ wvb, ushort* __restrict__ wob,
                        ushort* __restrict__ wqb, ushort* __restrict__ xcb,
                        ushort* __restrict__ wkT, float* __restrict__ bcent) {
  __shared__ ushort tile[32][33];
  int b = blockIdx.x;
  if (b == 784) {
    int i = threadIdx.x;
#pragma unroll
    for (int p = 0; p < 4; ++p) bcent[i + p * 256] = (float)((i + p * 256) >> 5);
    return;
  }
  if (b >= 785) {
    int b2 = b - 785;
    int bd = b2 >> 4, bk = b2 & 15;
    int t = threadIdx.x, lr = t >> 5, lc = t & 31;
#pragma unroll
    for (int p = 0; p < 4; ++p) {
      int rr = lr + p * 8;
      tile[rr][lc] = f2bf(0.125f * wk[(long)(bd * 32 + rr) * EMB + bk * 32 + lc]);
    }
    __syncthreads();
#pragma unroll
    for (int p = 0; p < 4; ++p) {
      int rr = lr + p * 8;
      wkT[(long)(bk * 32 + rr) * EMB + bd * 32 + lc] = tile[lc][rr];
    }
    return;
  }
  const float* src; ushort* dst; int off;
  if (b < 256)       { src = wv; dst = wvb; off = b; }
  else if (b < 512)  { src = wo; dst = wob; off = b - 256; }
  else if (b < 768)  { src = wq; dst = wqb; off = b - 512; }
  else               { src = xc; dst = xcb; off = b - 768; }
  int i = (off * 256 + threadIdx.x) * 4;
  float4 v = *reinterpret_cast<const float4*>(src + i);
  ushort4 o;
  o.x = f2bf(v.x); o.y = f2bf(v.y); o.z = f2bf(v.z); o.w = f2bf(v.w);
  *reinterpret_cast<ushort4*>(dst + i) = o;
}

// ---- per-(head, col-quarter) MFMA: Q_h then PC_h col slice ----
__global__ __launch_bounds__(256) void qpc_mfma(
    const ushort* __restrict__ xcb, const ushort* __restrict__ wqb,
    const float* __restrict__ bq, const ushort* __restrict__ wkTb,
    ushort* __restrict__ PCb) {
  __shared__ ushort Qs[32][72];
  int h = blockIdx.x >> 2, qs = blockIdx.x & 3;
  int t = threadIdx.x, w = t >> 6, lane = t & 63;
  int lr = lane & 15, grp = lane >> 4, ko = grp * 8;

  f32x4 qa[2];
  qa[0] = (f32x4)(0.0f); qa[1] = (f32x4)(0.0f);
#pragma unroll 4
  for (int kk = 0; kk < EMB; kk += 32) {
    short8 a0 = *reinterpret_cast<const short8*>(xcb + lr * EMB + kk + ko);
    short8 a1 = *reinterpret_cast<const short8*>(xcb + (16 + lr) * EMB + kk + ko);
    short8 b  = *reinterpret_cast<const short8*>(wqb + (long)(h * 64 + w * 16 + lr) * EMB + kk + ko);
    qa[0] = __builtin_amdgcn_mfma_f32_16x16x32_bf16(a0, b, qa[0], 0, 0, 0);
    qa[1] = __builtin_amdgcn_mfma_f32_16x16x32_bf16(a1, b, qa[1], 0, 0, 0);
  }
  float bias = bq[h * 64 + w * 16 + lr];
#pragma unroll
  for (int i = 0; i < 2; ++i)
#pragma unroll
    for (int r = 0; r < 4; ++r)
      Qs[i * 16 + grp * 4 + r][w * 16 + lr] = f2bf(qa[i][r] + bias);
  __syncthreads();

  f32x4 pa[2][2];
#pragma unroll
  for (int i = 0; i < 2; ++i)
#pragma unroll
    for (int j = 0; j < 2; ++j) pa[i][j] = (f32x4)(0.0f);
#pragma unroll
  for (int kk = 0; kk < 64; kk += 32) {
    short8 a0 = *reinterpret_cast<const short8*>(&Qs[lr][kk + ko]);
    short8 a1 = *reinterpret_cast<const short8*>(&Qs[16 + lr][kk + ko]);
#pragma unroll
    for (int j = 0; j < 2; ++j) {
      short8 b = *reinterpret_cast<const short8*>(
          wkTb + (long)(qs * 128 + w * 32 + j * 16 + lr) * EMB + h * 64 + kk + ko);
      pa[0][j] = __builtin_amdgcn_mfma_f32_16x16x32_bf16(a0, b, pa[0][j], 0, 0, 0);
      pa[1][j] = __builtin_amdgcn_mfma_f32_16x16x32_bf16(a1, b, pa[1][j], 0, 0, 0);
    }
  }
#pragma unroll
  for (int i = 0; i < 2; ++i)
#pragma unroll
    for (int j = 0; j < 2; ++j)
#pragma unroll
      for (int r = 0; r < 4; ++r)
        PCb[(long)(h * 32 + i * 16 + grp * 4 + r) * EMB + qs * 128 + w * 32 + j * 16 + lr] =
            f2bf(pa[i][j][r]);
}

// ---- fused attention per (graph, head): 16 waves, barrier-free K-loops ----
// Wave w owns a 32-col slice; stages AND reads only rows w*32..w*32+32 of Bbuf.
__global__ __launch_bounds__(1024) void fused_attn(
    const ushort* __restrict__ PCb, const ushort* __restrict__ xb,
    const ushort* __restrict__ xbT, const ushort* __restrict__ wvb,
    const float* __restrict__ bvb, ushort* __restrict__ aout) {
  __shared__ ushort PCl[32 * PST];
  __shared__ ushort PBuf[32 * PST];
  __shared__ ushort Bbuf[2][16384];   // [buf][512 rows][32 K]
  __shared__ float rmax[32][16];
  __shared__ float rsum[32][16];

  const int g = blockIdx.x & 31, h = blockIdx.x >> 5;  // g%8 == blk%8 -> XCD pinning
  const int t = threadIdx.x, w = t >> 6, lane = t & 63;
  const int lr = lane & 15, grp = lane >> 4;
  const int koU = grp * 8;

  const ushort* xg  = xb  + (long)g * NPG * EMB;
  const ushort* xTg = xbT + g * NPG;

  const int srow0 = w * 32 + (lane >> 2);
  const int spart = lane & 3;

  auto STAGE1 = [&](int c, int db) {
#pragma unroll
    for (int q = 0; q < 2; ++q) {
      int row = srow0 + q * 16;
      int psrc = spart ^ ((row >> 1) & 3);
      gload_lds16(xg + (long)row * EMB + c * 32 + psrc * 8,
                  &Bbuf[db][(w * 32 + q * 16) * 32]);
    }
  };
  auto STAGE3 = [&](int c, int db) {
#pragma unroll
    for (int q = 0; q < 2; ++q) {
      int row = srow0 + q * 16;
      int psrc = spart ^ ((row >> 1) & 3);
      gload_lds16(xTg + (long)row * NNODES + c * 32 + psrc * 8,
                  &Bbuf[db][(w * 32 + q * 16) * 32]);
    }
  };

  STAGE1(0, 0);
  STAGE1(1, 1);
  // stage PC_h into padded LDS
  {
    const ushort* pc = PCb + h * 32 * EMB;
#pragma unroll
    for (int p = 0; p < 2; ++p) {
      int u = t + p * 1024;
      int row = u >> 6, col = (u & 63) * 8;
      *reinterpret_cast<short8*>(&PCl[row * PST + col]) =
          *reinterpret_cast<const short8*>(pc + row * EMB + col);
    }
  }
  BARRIER_LGKM();

  // ---------- phase 1: S = PC_h · X_g^T ; NO barriers ----------
  f32x4 acc[2][2];
#pragma unroll
  for (int i = 0; i < 2; ++i)
#pragma unroll
    for (int j = 0; j < 2; ++j) acc[i][j] = (f32x4)(0.0f);

#pragma unroll
  for (int c = 0; c < 16; ++c) {
    const int db = c & 1;
    asm volatile("s_waitcnt vmcnt(2)" ::: "memory");   // chunk c landed; c+1 in flight
    __builtin_amdgcn_sched_barrier(0);
    short8 a0 = *reinterpret_cast<const short8*>(&PCl[lr * PST + c * 32 + koU]);
    short8 a1 = *reinterpret_cast<const short8*>(&PCl[(16 + lr) * PST + c * 32 + koU]);
    short8 bv[2];
#pragma unroll
    for (int j = 0; j < 2; ++j) {
      int n = w * 32 + j * 16 + lr;
      int psrc = grp ^ ((n >> 1) & 3);
      bv[j] = *reinterpret_cast<const short8*>(&Bbuf[db][n * 32 + psrc * 8]);
    }
#pragma unroll
    for (int j = 0; j < 2; ++j) {
      acc[0][j] = __builtin_amdgcn_mfma_f32_16x16x32_bf16(a0, bv[j], acc[0][j], 0, 0, 0);
      acc[1][j] = __builtin_amdgcn_mfma_f32_16x16x32_bf16(a1, bv[j], acc[1][j], 0, 0, 0);
    }
    __builtin_amdgcn_sched_barrier(0);
    if (c < 14) STAGE1(c + 2, db);
    else        STAGE3(c - 14, db);
  }

  // ---------- phase 2: softmax (cols split 16 ways) ----------
#pragma unroll
  for (int i = 0; i < 2; ++i)
#pragma unroll
    for (int r = 0; r < 4; ++r) {
      float m = fmaxf(acc[i][0][r], acc[i][1][r]);
      m = fmaxf(m, __shfl_xor(m, 1)); m = fmaxf(m, __shfl_xor(m, 2));
      m = fmaxf(m, __shfl_xor(m, 4)); m = fmaxf(m, __shfl_xor(m, 8));
      if (lr == 0) rmax[i * 16 + grp * 4 + r][w] = m;
    }
  BARRIER_LGKM();
#pragma unroll
  for (int i = 0; i < 2; ++i)
#pragma unroll
    for (int r = 0; r < 4; ++r) {
      int row = i * 16 + grp * 4 + r;
      float m = rmax[row][0];
#pragma unroll
      for (int q = 1; q < 16; ++q) m = fmaxf(m, rmax[row][q]);
      float s = 0.f;
#pragma unroll
      for (int j = 0; j < 2; ++j) {
        float e = __expf(acc[i][j][r] - m);
        acc[i][j][r] = e;
        s += e;
      }
      s += __shfl_xor(s, 1); s += __shfl_xor(s, 2);
      s += __shfl_xor(s, 4); s += __shfl_xor(s, 8);
      if (lr == 0) rsum[row][w] = s;
    }
  BARRIER_LGKM();
#pragma unroll
  for (int i = 0; i < 2; ++i)
#pragma unroll
    for (int r = 0; r < 4; ++r) {
      int row = i * 16 + grp * 4 + r;
      float tot = rsum[row][0];
#pragma unroll
      for (int q = 1; q < 16; ++q) tot += rsum[row][q];
      float inv = 1.f / tot;
#pragma unroll
      for (int j = 0; j < 2; ++j)
        PBuf[row * PST + w * 32 + j * 16 + lr] = f2bf(acc[i][j][r] * inv);
    }
  BARRIER_LGKM();   // attn ready in PBuf

  // ---------- phase 3: R = attn · X_g ; NO barriers ----------
  f32x4 acc2[2][2];
#pragma unroll
  for (int i = 0; i < 2; ++i)
#pragma unroll
    for (int j = 0; j < 2; ++j) acc2[i][j] = (f32x4)(0.0f);

#pragma unroll
  for (int c = 0; c < 16; ++c) {
    const int db = c & 1;
    if (c < 15) asm volatile("s_waitcnt vmcnt(2)" ::: "memory");
    else        asm volatile("s_waitcnt vmcnt(0)" ::: "memory");
    __builtin_amdgcn_sched_barrier(0);
    short8 a0 = *reinterpret_cast<const short8*>(&PBuf[lr * PST + c * 32 + koU]);
    short8 a1 = *reinterpret_cast<const short8*>(&PBuf[(16 + lr) * PST + c * 32 + koU]);
    short8 bv[2];
#pragma unroll
    for (int j = 0; j < 2; ++j) {
      int e = w * 32 + j * 16 + lr;
      int psrc = grp ^ ((e >> 1) & 3);
      bv[j] = *reinterpret_cast<const short8*>(&Bbuf[db][e * 32 + psrc * 8]);
    }
#pragma unroll
    for (int j = 0; j < 2; ++j) {
      acc2[0][j] = __builtin_amdgcn_mfma_f32_16x16x32_bf16(a0, bv[j], acc2[0][j], 0, 0, 0);
      acc2[1][j] = __builtin_amdgcn_mfma_f32_16x16x32_bf16(a1, bv[j], acc2[1][j], 0, 0, 0);
    }
    __builtin_amdgcn_sched_barrier(0);
    if (c < 14) STAGE3(c + 2, db);
  }
  BARRIER_LGKM();   // all waves done reading attn in PBuf

  // write R into PBuf
#pragma unroll
  for (int i = 0; i < 2; ++i)
#pragma unroll
    for (int r = 0; r < 4; ++r) {
      int row = i * 16 + grp * 4 + r;
#pragma unroll
      for (int j = 0; j < 2; ++j)
        PBuf[row * PST + w * 32 + j * 16 + lr] = f2bf(acc2[i][j][r]);
    }
  BARRIER_LGKM();   // R ready

  // ---------- phase 4: out = R · wv_h^T + bv_h (waves 0..7) ----------
  if (w < 8) {
    int wr = w >> 2, wc = w & 3;
    f32x4 acc3 = (f32x4)(0.0f);
    const ushort* wvh = wvb + (long)(h * 64 + wc * 16) * EMB;
#pragma unroll
    for (int c = 0; c < 16; ++c) {
      short8 a = *reinterpret_cast<const short8*>(&PBuf[(wr * 16 + lr) * PST + c * 32 + koU]);
      short8 b = *reinterpret_cast<const short8*>(wvh + (long)lr * EMB + c * 32 + koU);
      acc3 = __builtin_amdgcn_mfma_f32_16x16x32_bf16(a, b, acc3, 0, 0, 0);
    }
    float bias = bvb[h * 64 + wc * 16 + lr];
#pragma unroll
    for (int r = 0; r < 4; ++r) {
      int row = wr * 16 + grp * 4 + r;
      aout[(long)(g * 32 + row) * EMB + h * 64 + wc * 16 + lr] = f2bf(acc3[r] + bias);
    }
  }
}

// ---- generic C = A·B^T (+bias) GEMM (out_proj only) ----
template <int KK, int FM, int FN, int WM, int WN, bool OUT_BF16, bool HAS_BIAS>
__global__ void gemm_abt(const ushort* __restrict__ A, const ushort* __restrict__ Bm,
                         void* __restrict__ C, const float* __restrict__ bias,
                         int lda, int ldb, int ldc) {
  int tid = threadIdx.x;
  int wave = tid >> 6, lane = tid & 63;
  int wr = wave / WN, wc = wave % WN;
  int rowBase = blockIdx.y * (WM * FM * 16) + wr * FM * 16;
  int colBase = blockIdx.x * (WN * FN * 16) + wc * FN * 16;
  int lr = lane & 15;
  int ko = (lane >> 4) * 8;

  f32x4 acc[FM][FN];
#pragma unroll
  for (int i = 0; i < FM; ++i)
#pragma unroll
    for (int j = 0; j < FN; ++j) acc[i][j] = (f32x4)(0.0f);

#pragma unroll 8
  for (int kk = 0; kk < KK; kk += 32) {
    short8 av[FM], bv[FN];
#pragma unroll
    for (int i = 0; i < FM; ++i)
      av[i] = *reinterpret_cast<const short8*>(A + (long)(rowBase + i * 16 + lr) * lda + kk + ko);
#pragma unroll
    for (int j = 0; j < FN; ++j)
      bv[j] = *reinterpret_cast<const short8*>(Bm + (long)(colBase + j * 16 + lr) * ldb + kk + ko);
#pragma unroll
    for (int i = 0; i < FM; ++i)
#pragma unroll
      for (int j = 0; j < FN; ++j)
        acc[i][j] = __builtin_amdgcn_mfma_f32_16x16x32_bf16(av[i], bv[j], acc[i][j], 0, 0, 0);
  }

  int or0 = (lane >> 4) * 4;
#pragma unroll
  for (int i = 0; i < FM; ++i) {
#pragma unroll
    for (int j = 0; j < FN; ++j) {
      int col = colBase + j * 16 + lr;
      float bval = HAS_BIAS ? bias[col] : 0.f;
#pragma unroll
      for (int r = 0; r < 4; ++r) {
        int row = rowBase + i * 16 + or0 + r;
        float v = acc[i][j][r] + bval;
        if (OUT_BF16)
          ((ushort*)C)[(long)row * ldc + col] = f2bf(v);
        else
          ((float*)C)[(long)row * ldc + col] = v;
      }
    }
  }
}

extern "C" void kernel_launch(void* const* d_in, const int* in_sizes, int n_in,
                              void* d_out, int out_size, void* d_ws, size_t ws_size,
                              hipStream_t stream) {
  const float* x          = (const float*)d_in[0];
  const float* xcent_base = (const float*)d_in[3];
  const float* in_proj_w  = (const float*)d_in[4];
  const float* in_proj_b  = (const float*)d_in[5];
  const float* out_proj_w = (const float*)d_in[6];
  const float* out_proj_b = (const float*)d_in[7];

  char* w = (char*)d_ws;
  ushort* xb   = (ushort*)(w);                 // 16 MiB
  ushort* xbT  = (ushort*)(w + 16777216);      // 16 MiB
  ushort* PCb  = (ushort*)(w + 33554432);      // 256 KiB
  ushort* wvb  = (ushort*)(w + 33816576);      // 512 KiB
  ushort* wob  = (ushort*)(w + 34340864);      // 512 KiB
  ushort* wqb  = (ushort*)(w + 34865152);      // 512 KiB
  ushort* wkTb = (ushort*)(w + 35389440);      // 512 KiB
  ushort* xcb  = (ushort*)(w + 35913728);      // 32 KiB
  ushort* aout = (ushort*)(w + 35946496);      // 1 MiB

  const float* wq = in_proj_w;
  const float* wk = in_proj_w + 512 * 512;
  const float* wv = in_proj_w + 1024 * 512;
  const float* bq = in_proj_b;
  const float* bv = in_proj_b + 1024;

  prep_x<<<2048, 256, 0, stream>>>(x, xb, xbT);
  prep_wb<<<1041, 256, 0, stream>>>(wv, out_proj_w, wq, xcent_base, wk,
                                    wvb, wob, wqb, xcb, wkTb,
                                    (float*)d_out + LQ * EMB);
  qpc_mfma<<<32, 256, 0, stream>>>(xcb, wqb, bq, wkTb, PCb);

  fused_attn<<<256, 1024, 0, stream>>>(PCb, xb, xbT, wvb, bv, aout);

  gemm_abt<512, 1, 2, 2, 2, false, true><<<dim3(8, 32, 1), 256, 0, stream>>>(
      aout, wob, d_out, out_proj_b, 512, 512, 512);
}